// Round 2
// baseline (867.651 us; speedup 1.0000x reference)
//
#include <hip/hip_runtime.h>
#include <hip/hip_bf16.h>

#define DEV __device__ __forceinline__

typedef __attribute__((ext_vector_type(8))) short bf16x8;
typedef __attribute__((ext_vector_type(4))) float f32x4;

constexpr int Bb = 2, V = 65536, CIN = 128, COUT = 256, TDIM = 512;
constexpr float EPS = 1e-5f;
constexpr int K1 = 1152, K2 = 2304, K2e = 2432;
constexpr int NCH1 = 128;   // gn1 chunks (512 rows each)
constexpr int NCH2 = 256;   // gn2 chunks (256 rows each)
constexpr int W1N = (K1/8)*COUT*8;    // 294912
constexpr int W2N = (K2e/8)*COUT*8;   // 622592

DEV float silu_f(float x){ return x / (1.f + __expf(-x)); }
DEV unsigned short f2b(float x){
  union { float f; unsigned u; } v; v.f = x;
  unsigned r = v.u + 0x7fffu + ((v.u >> 16) & 1u);
  return (unsigned short)(r >> 16);
}
DEV float b2f(unsigned short h){ union { unsigned u; float f; } v; v.u = ((unsigned)h) << 16; return v.f; }

// ---------------- gn1 stats ----------------
__global__ void k_gn1_partial(const float* __restrict__ x, float* __restrict__ part){
  int b = blockIdx.y, ch = blockIdx.x;
  int t = threadIdx.x;            // 256
  int c = t & 127;
  int r0 = t >> 7;                // 0..1
  float s = 0.f, ss = 0.f;
  const float* xp = x + ((size_t)b*V + (size_t)ch*512)*CIN + c;
  for (int r = r0; r < 512; r += 2){
    float v = xp[(size_t)r*CIN];
    s += v; ss += v*v;
  }
  __shared__ float s_s[256], s_q[256];
  s_s[t] = s; s_q[t] = ss; __syncthreads();
  if (t < 128){ s_s[t] += s_s[t+128]; s_q[t] += s_q[t+128]; }
  __syncthreads();
  if (t < 32){
    float a = 0, q = 0;
    for (int i = 0; i < 4; ++i){ a += s_s[t*4+i]; q += s_q[t*4+i]; }
    int idx = ((b*32 + t)*NCH1 + ch)*2;
    part[idx] = a; part[idx+1] = q;
  }
}

__global__ void k_gn1_final(const float* __restrict__ part, const float* __restrict__ w,
                            const float* __restrict__ bias, float* __restrict__ sc,
                            float* __restrict__ bi){
  int t = threadIdx.x;  // 64 = b*32+g
  if (t >= Bb*32) return;
  float s = 0, q = 0;
  for (int ch = 0; ch < NCH1; ++ch){ s += part[(t*NCH1+ch)*2]; q += part[(t*NCH1+ch)*2+1]; }
  float n = (float)V * 4.f;
  float mean = s / n;
  float var = q / n - mean*mean;
  float inv = rsqrtf(var + EPS);
  int b = t >> 5, g = t & 31;
  for (int j = 0; j < 4; ++j){
    int c = g*4 + j;
    float scl = w[c] * inv;
    sc[b*CIN + c] = scl;
    bi[b*CIN + c] = bias[c] - mean*scl;
  }
}

// act1 = bf16(silu(gn1(x))), xb = bf16(x)
__global__ void k_act1(const float* __restrict__ x, const float* __restrict__ sc,
                       const float* __restrict__ bi, unsigned short* __restrict__ act1,
                       unsigned short* __restrict__ xb){
  size_t i = ((size_t)blockIdx.x*256 + threadIdx.x)*4;
  int c = (int)(i & (CIN-1));
  int b = (int)(i >> 23);
  float4 v = *(const float4*)(x + i);
  const float* scp = sc + b*CIN + c;
  const float* bip = bi + b*CIN + c;
  ushort4 a, xo;
  a.x = f2b(silu_f(v.x*scp[0] + bip[0]));
  a.y = f2b(silu_f(v.y*scp[1] + bip[1]));
  a.z = f2b(silu_f(v.z*scp[2] + bip[2]));
  a.w = f2b(silu_f(v.w*scp[3] + bip[3]));
  xo.x = f2b(v.x); xo.y = f2b(v.y); xo.z = f2b(v.z); xo.w = f2b(v.w);
  *(ushort4*)(act1 + i) = a;
  *(ushort4*)(xb + i)   = xo;
}

// W layouts: Wb[k8][o][j] = W[o][k8*8+j], bf16. W2b gets ws appended at k>=2304.
__global__ void k_prepW(const float* __restrict__ w1, const float* __restrict__ w2,
                        const float* __restrict__ wsm, unsigned short* __restrict__ W1b,
                        unsigned short* __restrict__ W2b){
  int i = blockIdx.x*256 + threadIdx.x;
  if (i < W1N){
    int j = i & 7, o = (i >> 3) & 255, k8 = i >> 11;
    W1b[i] = f2b(w1[o*K1 + k8*8 + j]);
  }
  int i2 = i - W1N;
  if (i2 >= 0 && i2 < W2N){
    int j = i2 & 7, o = (i2 >> 3) & 255, k8 = i2 >> 11;
    int k = k8*8 + j;
    float v = (k < K2) ? w2[o*K2 + k] : wsm[o*CIN + (k - K2)];
    W2b[i2] = f2b(v);
  }
}

// tcomb[b][o] = silu(t_emb[b]) @ wt[o] + bt[o] + b1[o]
// One wave per output: coalesced wt reads + shuffle reduce.
__global__ void k_tcomb(const float* __restrict__ temb, const float* __restrict__ wt,
                        const float* __restrict__ bt, const float* __restrict__ b1,
                        float* __restrict__ tc){
  int b = blockIdx.y;
  int o = blockIdx.x*4 + (threadIdx.x >> 6);
  int l = threadIdx.x & 63;
  const float* tb = temb + (size_t)b*TDIM;
  const float* wr = wt + (size_t)o*TDIM;
  float acc = 0.f;
  #pragma unroll
  for (int k = l; k < TDIM; k += 64)
    acc += silu_f(tb[k]) * wr[k];
  #pragma unroll
  for (int off = 32; off > 0; off >>= 1) acc += __shfl_down(acc, off, 64);
  if (l == 0) tc[b*COUT + o] = acc + bt[o] + b1[o];
}

// ---------------- gathered GEMM, all-register barrier-free ----------------
// Tile: 128(M) x 128(N), 4 waves (each 64x64), BK=64, 16x16x32 bf16 MFMA.
// NO LDS staging: the MFMA fragment layout (lane: row=l15, k-slice=quad) makes
// each lane's A and B fragment a single contiguous 16B global load:
//   A(mt,ks): act[rowg][c0 + (ks*4+quad)*8 ..+8)   rowg = nb[row*9+nidx]
//   B(nt,ks): Wb[chunk*8 + ks*4+quad][n0+wn*64+nt*16+l15][0..8)
// One A instr = 16 rows x 64B fully-used lines; B is contiguous per quad.
// Ping-pong register sets (a0/b0, a1/b1) give a one-chunk issue-to-use
// distance; the compiler tracks the load->MFMA register deps and inserts
// counted vmcnt waits itself (no barrier, no drain). Round-1 lesson: the
// LDS double-buffer's barrier+vmcnt(0)-style drain burst-synchronized 256
// random line requests per block-chunk -> queueing inflated latency to
// multiple-1000s of cycles; barrier-free continuous issue smooths the queue
// and decorrelates the waves. A is read by both wn-waves of a block (same-CU
// L1 hits); B (1.2 MB) is L2-resident for all CUs.
// XCD pair swizzle kept: blocks (bx,n0=0)/(bx,n0=128) gather the SAME rows;
// mapped 8 dispatches apart -> same XCD -> L2 gather reuse (FETCH 595->303MB).
template<int CINR, int NCHUNK, int CPN, bool CONV2>
__launch_bounds__(256, 2)
__global__ void k_conv(const unsigned short* __restrict__ act,
                       const unsigned short* __restrict__ xb,
                       const unsigned short* __restrict__ Wb,
                       const int* __restrict__ neigh,
                       const float* __restrict__ tc,
                       const float* __restrict__ b2,
                       const float* __restrict__ bs,
                       unsigned short* __restrict__ outb,
                       float* __restrict__ outf){
  __shared__ int nb[128*9];
  const int tid = threadIdx.x;
  const int w = tid >> 6, lane = tid & 63;
  const int d = blockIdx.x;                    // 0..2047
  const int bx = ((d >> 4) << 3) + (d & 7);    // row-block 0..1023
  const int n0 = ((d >> 3) & 1) << 7;          // N-half; pair d,d+8 -> same XCD
  const int vflat = bx << 7;
  const int b = vflat >> 16;          // / V
  const int vb = vflat & (V-1);
  for (int i = tid; i < 128*9; i += 256) nb[i] = neigh[(size_t)vb*9 + i];

  f32x4 acc[4][4] = {};
  const int wm = w >> 1, wn = w & 1;
  const int quad = lane >> 4, l15 = lane & 15;

  const unsigned short* actb = act + (size_t)b*V*CINR;
  const unsigned short* xbb  = CONV2 ? (xb + (size_t)b*V*CIN) : (const unsigned short*)nullptr;
  // per-lane base into Wb for this wave's N-columns and k-slice quad
  const unsigned short* wq = Wb + (size_t)quad*COUT*8 + (size_t)(n0 + (wn<<6) + l15)*8;

  __syncthreads();   // nb visible

  // issue chunk's 16 fragment loads into the named register sets
  auto ISSUE = [&](int chunk, bf16x8 (&av)[8], bf16x8 (&bv)[8]){
    const bool scseg = CONV2 && (chunk >= NCHUNK-2);
    int nidx = 0, c0, rl;
    const unsigned short* src;
    if (scseg){ c0 = (chunk - (NCHUNK-2))*64; src = xbb; rl = CIN; }
    else      { nidx = chunk / CPN; c0 = (chunk % CPN)*64; src = actb; rl = CINR; }
    #pragma unroll
    for (int mt = 0; mt < 4; ++mt){
      int row = (wm<<6) + (mt<<4) + l15;
      int rowg = scseg ? (vb + row) : nb[row*9 + nidx];
      const unsigned short* rp = src + (size_t)rowg*rl + c0 + (quad<<3);
      av[mt*2+0] = *(const bf16x8*)(rp);        // ks=0: k-bytes [quad*16)
      av[mt*2+1] = *(const bf16x8*)(rp + 32);   // ks=1: +32 elements
    }
    const unsigned short* wp = wq + (size_t)chunk*8*COUT*8;
    #pragma unroll
    for (int nt = 0; nt < 4; ++nt){
      bv[nt*2+0] = *(const bf16x8*)(wp + (nt<<7));               // ks=0
      bv[nt*2+1] = *(const bf16x8*)(wp + 4*COUT*8 + (nt<<7));    // ks=1
    }
  };

  auto COMP = [&](bf16x8 (&av)[8], bf16x8 (&bv)[8]){
    #pragma unroll
    for (int ks = 0; ks < 2; ++ks)
      #pragma unroll
      for (int mt = 0; mt < 4; ++mt)
        #pragma unroll
        for (int nt = 0; nt < 4; ++nt)
          acc[mt][nt] = __builtin_amdgcn_mfma_f32_16x16x32_bf16(av[mt*2+ks], bv[nt*2+ks], acc[mt][nt], 0, 0, 0);
  };

  bf16x8 a0[8], b0[8], a1[8], b1[8];
  ISSUE(0, a0, b0);
  #pragma unroll 1
  for (int c = 0; c < NCHUNK; c += 2){         // NCHUNK even (18 / 38)
    ISSUE(c+1, a1, b1);                        // always valid: c+1 <= NCHUNK-1
    COMP(a0, b0);
    if (c+2 < NCHUNK) ISSUE(c+2, a0, b0);
    COMP(a1, b1);
  }

  // ---- epilogue: C/D layout col=lane&15, row=quad*4+reg (m89-verified)
  #pragma unroll
  for (int mt = 0; mt < 4; ++mt){
    #pragma unroll
    for (int nt = 0; nt < 4; ++nt){
      int col = n0 + (wn<<6) + (nt<<4) + l15;
      float bval = CONV2 ? (b2[col] + bs[col]) : tc[b*COUT + col];
      #pragma unroll
      for (int rg = 0; rg < 4; ++rg){
        int row = (wm<<6) + (mt<<4) + (quad<<2) + rg;
        size_t off = ((size_t)(vflat + row))*COUT + col;
        float v = acc[mt][nt][rg] + bval;
        if (CONV2) outf[off] = v;
        else       outb[off] = f2b(v);
      }
    }
  }
}

// ---------------- gn2 stats on bf16 h1 ----------------
__global__ void k_gn2_partial(const unsigned short* __restrict__ h1, float* __restrict__ part){
  int b = blockIdx.y, ch = blockIdx.x;
  int t = threadIdx.x;  // 256 = channel
  float s = 0.f, ss = 0.f;
  const unsigned short* p = h1 + ((size_t)b*V + (size_t)ch*256)*COUT + t;
  for (int r = 0; r < 256; ++r){
    float v = b2f(p[(size_t)r*COUT]);
    s += v; ss += v*v;
  }
  __shared__ float s_s[256], s_q[256];
  s_s[t] = s; s_q[t] = ss; __syncthreads();
  if (t < 32){
    float a = 0, q = 0;
    for (int i = 0; i < 8; ++i){ a += s_s[t*8+i]; q += s_q[t*8+i]; }
    int idx = ((b*32 + t)*NCH2 + ch)*2;
    part[idx] = a; part[idx+1] = q;
  }
}

__global__ void k_gn2_final(const float* __restrict__ part, const float* __restrict__ w,
                            const float* __restrict__ bias, float* __restrict__ sc,
                            float* __restrict__ bi){
  int t = threadIdx.x;
  if (t >= Bb*32) return;
  float s = 0, q = 0;
  for (int ch = 0; ch < NCH2; ++ch){ s += part[(t*NCH2+ch)*2]; q += part[(t*NCH2+ch)*2+1]; }
  float n = (float)V * 8.f;
  float mean = s / n, var = q / n - mean*mean, inv = rsqrtf(var + EPS);
  int b = t >> 5, g = t & 31;
  for (int j = 0; j < 8; ++j){
    int c = g*8 + j;
    float scl = w[c] * inv;
    sc[b*COUT + c] = scl;
    bi[b*COUT + c] = bias[c] - mean*scl;
  }
}

// act2 = silu(gn2(h1)) in place (bf16)
__global__ void k_act2(unsigned short* __restrict__ h1, const float* __restrict__ sc,
                       const float* __restrict__ bi){
  size_t i = ((size_t)blockIdx.x*256 + threadIdx.x)*4;
  int c = (int)(i & (COUT-1));
  int b = (int)(i >> 24);
  ushort4 h = *(ushort4*)(h1 + i);
  const float* scp = sc + b*COUT + c;
  const float* bip = bi + b*COUT + c;
  ushort4 o;
  o.x = f2b(silu_f(b2f(h.x)*scp[0] + bip[0]));
  o.y = f2b(silu_f(b2f(h.y)*scp[1] + bip[1]));
  o.z = f2b(silu_f(b2f(h.z)*scp[2] + bip[2]));
  o.w = f2b(silu_f(b2f(h.w)*scp[3] + bip[3]));
  *(ushort4*)(h1 + i) = o;
}

extern "C" void kernel_launch(void* const* d_in, const int* in_sizes, int n_in,
                              void* d_out, int out_size, void* d_ws, size_t ws_size,
                              hipStream_t stream){
  const float* x    = (const float*)d_in[0];
  const float* temb = (const float*)d_in[1];
  const int*   neigh= (const int*)d_in[2];
  const float* gn1w = (const float*)d_in[3];
  const float* gn1b = (const float*)d_in[4];
  const float* w1   = (const float*)d_in[5];
  const float* b1   = (const float*)d_in[6];
  const float* wt   = (const float*)d_in[7];
  const float* bt   = (const float*)d_in[8];
  const float* gn2w = (const float*)d_in[9];
  const float* gn2b = (const float*)d_in[10];
  const float* w2   = (const float*)d_in[11];
  const float* b2   = (const float*)d_in[12];
  const float* wsm  = (const float*)d_in[13];
  const float* bs   = (const float*)d_in[14];
  float* out = (float*)d_out;

  char* wsp = (char*)d_ws;
  unsigned short* act1 = (unsigned short*)(wsp);                       // 32 MiB
  unsigned short* xb   = (unsigned short*)(wsp + 33554432);            // 32 MiB
  unsigned short* h1   = (unsigned short*)(wsp + 67108864);            // 64 MiB
  unsigned short* W1b  = (unsigned short*)(wsp + 134217728);           // 589824 B
  unsigned short* W2b  = (unsigned short*)(wsp + 134217728 + 589824);  // 1245184 B
  char* p = wsp + 134217728 + 589824 + 1245184;
  float* tc    = (float*)p;  p += 2048;
  float* part1 = (float*)p;  p += (size_t)Bb*32*NCH1*2*4;
  float* part2 = (float*)p;  p += (size_t)Bb*32*NCH2*2*4;
  float* sc1   = (float*)p;  p += 1024;
  float* bi1   = (float*)p;  p += 1024;
  float* sc2   = (float*)p;  p += 2048;
  float* bi2   = (float*)p;  p += 2048;

  k_gn1_partial<<<dim3(NCH1, Bb), 256, 0, stream>>>(x, part1);
  k_gn1_final  <<<1, 64, 0, stream>>>(part1, gn1w, gn1b, sc1, bi1);
  k_act1       <<<16384, 256, 0, stream>>>(x, sc1, bi1, act1, xb);
  k_prepW      <<<(W1N + W2N)/256, 256, 0, stream>>>(w1, w2, wsm, W1b, W2b);
  k_tcomb      <<<dim3(COUT/4, Bb), 256, 0, stream>>>(temb, wt, bt, b1, tc);
  k_conv<128, 18, 2, false><<<2048, 256, 0, stream>>>(act1, nullptr, W1b, neigh, tc, nullptr, nullptr, h1, nullptr);
  k_gn2_partial<<<dim3(NCH2, Bb), 256, 0, stream>>>(h1, part2);
  k_gn2_final  <<<1, 64, 0, stream>>>(part2, gn2w, gn2b, sc2, bi2);
  k_act2       <<<32768, 256, 0, stream>>>(h1, sc2, bi2);
  k_conv<256, 38, 4, true><<<2048, 256, 0, stream>>>(h1, xb, W2b, neigh, nullptr, b2, bs, nullptr, out);
}

// Round 3
// 625.163 us; speedup vs baseline: 1.3879x; 1.3879x over previous
//
#include <hip/hip_runtime.h>
#include <hip/hip_bf16.h>

#define DEV __device__ __forceinline__

typedef __attribute__((ext_vector_type(8))) short bf16x8;
typedef __attribute__((ext_vector_type(4))) float f32x4;

constexpr int Bb = 2, V = 65536, CIN = 128, COUT = 256, TDIM = 512;
constexpr float EPS = 1e-5f;
constexpr int K1 = 1152, K2 = 2304, K2e = 2432;
constexpr int NCH1 = 128;   // gn1 chunks (512 rows each)
constexpr int NCH2 = 256;   // gn2 chunks (256 rows each)
constexpr int W1N = (K1/8)*COUT*8;    // 294912
constexpr int W2N = (K2e/8)*COUT*8;   // 622592

DEV float silu_f(float x){ return x / (1.f + __expf(-x)); }
DEV unsigned short f2b(float x){
  union { float f; unsigned u; } v; v.f = x;
  unsigned r = v.u + 0x7fffu + ((v.u >> 16) & 1u);
  return (unsigned short)(r >> 16);
}
DEV float b2f(unsigned short h){ union { unsigned u; float f; } v; v.u = ((unsigned)h) << 16; return v.f; }

// ---------------- gn1 stats ----------------
__global__ void k_gn1_partial(const float* __restrict__ x, float* __restrict__ part){
  int b = blockIdx.y, ch = blockIdx.x;
  int t = threadIdx.x;            // 256
  int c = t & 127;
  int r0 = t >> 7;                // 0..1
  float s = 0.f, ss = 0.f;
  const float* xp = x + ((size_t)b*V + (size_t)ch*512)*CIN + c;
  for (int r = r0; r < 512; r += 2){
    float v = xp[(size_t)r*CIN];
    s += v; ss += v*v;
  }
  __shared__ float s_s[256], s_q[256];
  s_s[t] = s; s_q[t] = ss; __syncthreads();
  if (t < 128){ s_s[t] += s_s[t+128]; s_q[t] += s_q[t+128]; }
  __syncthreads();
  if (t < 32){
    float a = 0, q = 0;
    for (int i = 0; i < 4; ++i){ a += s_s[t*4+i]; q += s_q[t*4+i]; }
    int idx = ((b*32 + t)*NCH1 + ch)*2;
    part[idx] = a; part[idx+1] = q;
  }
}

__global__ void k_gn1_final(const float* __restrict__ part, const float* __restrict__ w,
                            const float* __restrict__ bias, float* __restrict__ sc,
                            float* __restrict__ bi){
  int t = threadIdx.x;  // 64 = b*32+g
  if (t >= Bb*32) return;
  float s = 0, q = 0;
  for (int ch = 0; ch < NCH1; ++ch){ s += part[(t*NCH1+ch)*2]; q += part[(t*NCH1+ch)*2+1]; }
  float n = (float)V * 4.f;
  float mean = s / n;
  float var = q / n - mean*mean;
  float inv = rsqrtf(var + EPS);
  int b = t >> 5, g = t & 31;
  for (int j = 0; j < 4; ++j){
    int c = g*4 + j;
    float scl = w[c] * inv;
    sc[b*CIN + c] = scl;
    bi[b*CIN + c] = bias[c] - mean*scl;
  }
}

// act1 = bf16(silu(gn1(x))), xb = bf16(x)
__global__ void k_act1(const float* __restrict__ x, const float* __restrict__ sc,
                       const float* __restrict__ bi, unsigned short* __restrict__ act1,
                       unsigned short* __restrict__ xb){
  size_t i = ((size_t)blockIdx.x*256 + threadIdx.x)*4;
  int c = (int)(i & (CIN-1));
  int b = (int)(i >> 23);
  float4 v = *(const float4*)(x + i);
  const float* scp = sc + b*CIN + c;
  const float* bip = bi + b*CIN + c;
  ushort4 a, xo;
  a.x = f2b(silu_f(v.x*scp[0] + bip[0]));
  a.y = f2b(silu_f(v.y*scp[1] + bip[1]));
  a.z = f2b(silu_f(v.z*scp[2] + bip[2]));
  a.w = f2b(silu_f(v.w*scp[3] + bip[3]));
  xo.x = f2b(v.x); xo.y = f2b(v.y); xo.z = f2b(v.z); xo.w = f2b(v.w);
  *(ushort4*)(act1 + i) = a;
  *(ushort4*)(xb + i)   = xo;
}

// W layouts: Wb[k8][o][j] = W[o][k8*8+j], bf16. W2b gets ws appended at k>=2304.
__global__ void k_prepW(const float* __restrict__ w1, const float* __restrict__ w2,
                        const float* __restrict__ wsm, unsigned short* __restrict__ W1b,
                        unsigned short* __restrict__ W2b){
  int i = blockIdx.x*256 + threadIdx.x;
  if (i < W1N){
    int j = i & 7, o = (i >> 3) & 255, k8 = i >> 11;
    W1b[i] = f2b(w1[o*K1 + k8*8 + j]);
  }
  int i2 = i - W1N;
  if (i2 >= 0 && i2 < W2N){
    int j = i2 & 7, o = (i2 >> 3) & 255, k8 = i2 >> 11;
    int k = k8*8 + j;
    float v = (k < K2) ? w2[o*K2 + k] : wsm[o*CIN + (k - K2)];
    W2b[i2] = f2b(v);
  }
}

// tcomb[b][o] = silu(t_emb[b]) @ wt[o] + bt[o] + b1[o]
// One wave per output: coalesced wt reads + shuffle reduce.
__global__ void k_tcomb(const float* __restrict__ temb, const float* __restrict__ wt,
                        const float* __restrict__ bt, const float* __restrict__ b1,
                        float* __restrict__ tc){
  int b = blockIdx.y;
  int o = blockIdx.x*4 + (threadIdx.x >> 6);
  int l = threadIdx.x & 63;
  const float* tb = temb + (size_t)b*TDIM;
  const float* wr = wt + (size_t)o*TDIM;
  float acc = 0.f;
  #pragma unroll
  for (int k = l; k < TDIM; k += 64)
    acc += silu_f(tb[k]) * wr[k];
  #pragma unroll
  for (int off = 32; off > 0; off >>= 1) acc += __shfl_down(acc, off, 64);
  if (l == 0) tc[b*COUT + o] = acc + bt[o] + b1[o];
}

// ---------------- gathered GEMM: hybrid (A via DMA->LDS, B direct to regs) ----
// Tile: 128(M) x 128(N), 4 waves (each 64x64), BK=64, 16x16x32 bf16 MFMA.
// Round-2 lesson: register ping-pong at HIP source is NOT schedulable -- the
// compiler sinks prefetch loads to their use, collapsing the pipeline (VGPR
// dropped to 108, MfmaUtil 18%). Round-1 lesson: LDS double-buffer costs 2
// blocks/CU and loses more than the pipeline gains. Hybrid: keep round-0's
// single-buffered DMA staging for the gathered A (the latency problem), but
// feed B straight to registers from L2-resident Wb (1.2 MB, shared via XCD
// pairing). B loads are issued BEFORE the barrier so their latency hides
// under the A-DMA drain. LDS drops 37.4->20.9 KB; with __launch_bounds__
// (256,4) we get 4 blocks/CU (vs round-0's ~2 effective) -> the per-chunk
// gather drain is covered by other resident blocks' MFMA phases.
// A-LDS: 128 rows x 64 el, XOR segment swizzle: slot s of row r holds global
// segment s^(r&7); DMA dst is uniform base + lane*16B (m104/m108), source
// address carries the swizzle.
// XCD pair swizzle: blocks (bx,n0=0)/(bx,n0=128) gather the SAME 128x9 rows;
// mapped 8 dispatches apart -> same XCD -> L2 gather reuse (FETCH 595->303MB).
template<int CINR, int NCHUNK, int CPN, bool CONV2>
__launch_bounds__(256, 4)
__global__ void k_conv(const unsigned short* __restrict__ act,
                       const unsigned short* __restrict__ xb,
                       const unsigned short* __restrict__ Wb,
                       const int* __restrict__ neigh,
                       const float* __restrict__ tc,
                       const float* __restrict__ b2,
                       const float* __restrict__ bs,
                       unsigned short* __restrict__ outb,
                       float* __restrict__ outf){
  __shared__ __align__(16) unsigned short A_lds[128*64];
  __shared__ int nb[128*9];
  const int tid = threadIdx.x;
  const int w = tid >> 6, lane = tid & 63;
  const int d = blockIdx.x;                    // 0..2047
  const int bx = ((d >> 4) << 3) + (d & 7);    // row-block 0..1023
  const int n0 = ((d >> 3) & 1) << 7;          // N-half; pair d,d+8 -> same XCD
  const int vflat = bx << 7;
  const int b = vflat >> 16;          // / V
  const int vb = vflat & (V-1);
  for (int i = tid; i < 128*9; i += 256) nb[i] = neigh[(size_t)vb*9 + i];

  f32x4 acc[4][4] = {};
  const int wm = w >> 1, wn = w & 1;
  const int quad = lane >> 4, l15 = lane & 15;
  const int sr = lane >> 3, ssg = lane & 7;

  const unsigned short* actb = act + (size_t)b*V*CINR;
  const unsigned short* xbb  = CONV2 ? (xb + (size_t)b*V*CIN) : (const unsigned short*)nullptr;
  // per-lane base into Wb for this wave's N-columns and k-slice quad
  const unsigned short* wq = Wb + (size_t)quad*COUT*8 + (size_t)(n0 + (wn<<6) + l15)*8;

  __syncthreads();   // nb visible

  #pragma unroll 1
  for (int chunk = 0; chunk < NCHUNK; ++chunk){
    // ---- stage A (gathered rows) via DMA: 4 issues/wave, 8 rows x 8 segs each
    {
      const bool scseg = CONV2 && (chunk >= NCHUNK-2);
      int nidx = 0, c0, rl;
      const unsigned short* src;
      if (scseg){ c0 = (chunk - (NCHUNK-2))*64; src = xbb; rl = CIN; }
      else      { nidx = chunk / CPN; c0 = (chunk % CPN)*64; src = actb; rl = CINR; }
      #pragma unroll
      for (int i = 0; i < 4; ++i){
        int row  = (w<<5) + (i<<3) + sr;
        int rowg = scseg ? (vb + row) : nb[row*9 + nidx];
        int g = ssg ^ (row & 7);
        const unsigned short* gp = src + (size_t)rowg*rl + c0 + g*8;   // per-lane src
        unsigned short* lp = A_lds + (((w<<5) + (i<<3))<<6);           // uniform dst
        __builtin_amdgcn_global_load_lds(gp, lp, 16, 0, 0);
      }
    }
    // ---- B fragments straight to regs (L2-resident); latency hides under drain
    bf16x8 bv[8];
    {
      const unsigned short* wp = wq + (size_t)chunk*8*COUT*8;
      #pragma unroll
      for (int nt = 0; nt < 4; ++nt){
        bv[nt*2+0] = *(const bf16x8*)(wp + (nt<<7));               // ks=0
        bv[nt*2+1] = *(const bf16x8*)(wp + 4*COUT*8 + (nt<<7));    // ks=1
      }
    }
    __syncthreads();   // vmcnt drain: A staged + visible, bv ready

    __builtin_amdgcn_s_setprio(1);
    #pragma unroll
    for (int ks = 0; ks < 2; ++ks){
      bf16x8 av[4];
      #pragma unroll
      for (int mt = 0; mt < 4; ++mt){
        int m = (wm<<6) + (mt<<4) + l15;
        int seg = ((ks<<2) + quad) ^ (l15 & 7);    // undo swizzle (m&7 == l15&7)
        av[mt] = *(const bf16x8*)&A_lds[(m<<6) + (seg<<3)];
      }
      #pragma unroll
      for (int mt = 0; mt < 4; ++mt)
        #pragma unroll
        for (int nt = 0; nt < 4; ++nt)
          acc[mt][nt] = __builtin_amdgcn_mfma_f32_16x16x32_bf16(av[mt], bv[nt*2+ks], acc[mt][nt], 0, 0, 0);
    }
    __builtin_amdgcn_s_setprio(0);
    __syncthreads();   // all A reads done before next chunk's stage
  }

  // ---- epilogue: C/D layout col=lane&15, row=quad*4+reg (m89-verified)
  #pragma unroll
  for (int mt = 0; mt < 4; ++mt){
    #pragma unroll
    for (int nt = 0; nt < 4; ++nt){
      int col = n0 + (wn<<6) + (nt<<4) + l15;
      float bval = CONV2 ? (b2[col] + bs[col]) : tc[b*COUT + col];
      #pragma unroll
      for (int rg = 0; rg < 4; ++rg){
        int row = (wm<<6) + (mt<<4) + (quad<<2) + rg;
        size_t off = ((size_t)(vflat + row))*COUT + col;
        float v = acc[mt][nt][rg] + bval;
        if (CONV2) outf[off] = v;
        else       outb[off] = f2b(v);
      }
    }
  }
}

// ---------------- gn2 stats on bf16 h1 ----------------
__global__ void k_gn2_partial(const unsigned short* __restrict__ h1, float* __restrict__ part){
  int b = blockIdx.y, ch = blockIdx.x;
  int t = threadIdx.x;  // 256 = channel
  float s = 0.f, ss = 0.f;
  const unsigned short* p = h1 + ((size_t)b*V + (size_t)ch*256)*COUT + t;
  for (int r = 0; r < 256; ++r){
    float v = b2f(p[(size_t)r*COUT]);
    s += v; ss += v*v;
  }
  __shared__ float s_s[256], s_q[256];
  s_s[t] = s; s_q[t] = ss; __syncthreads();
  if (t < 32){
    float a = 0, q = 0;
    for (int i = 0; i < 8; ++i){ a += s_s[t*8+i]; q += s_q[t*8+i]; }
    int idx = ((b*32 + t)*NCH2 + ch)*2;
    part[idx] = a; part[idx+1] = q;
  }
}

__global__ void k_gn2_final(const float* __restrict__ part, const float* __restrict__ w,
                            const float* __restrict__ bias, float* __restrict__ sc,
                            float* __restrict__ bi){
  int t = threadIdx.x;
  if (t >= Bb*32) return;
  float s = 0, q = 0;
  for (int ch = 0; ch < NCH2; ++ch){ s += part[(t*NCH2+ch)*2]; q += part[(t*NCH2+ch)*2+1]; }
  float n = (float)V * 8.f;
  float mean = s / n, var = q / n - mean*mean, inv = rsqrtf(var + EPS);
  int b = t >> 5, g = t & 31;
  for (int j = 0; j < 8; ++j){
    int c = g*8 + j;
    float scl = w[c] * inv;
    sc[b*COUT + c] = scl;
    bi[b*COUT + c] = bias[c] - mean*scl;
  }
}

// act2 = silu(gn2(h1)) in place (bf16)
__global__ void k_act2(unsigned short* __restrict__ h1, const float* __restrict__ sc,
                       const float* __restrict__ bi){
  size_t i = ((size_t)blockIdx.x*256 + threadIdx.x)*4;
  int c = (int)(i & (COUT-1));
  int b = (int)(i >> 24);
  ushort4 h = *(ushort4*)(h1 + i);
  const float* scp = sc + b*COUT + c;
  const float* bip = bi + b*COUT + c;
  ushort4 o;
  o.x = f2b(silu_f(b2f(h.x)*scp[0] + bip[0]));
  o.y = f2b(silu_f(b2f(h.y)*scp[1] + bip[1]));
  o.z = f2b(silu_f(b2f(h.z)*scp[2] + bip[2]));
  o.w = f2b(silu_f(b2f(h.w)*scp[3] + bip[3]));
  *(ushort4*)(h1 + i) = o;
}

extern "C" void kernel_launch(void* const* d_in, const int* in_sizes, int n_in,
                              void* d_out, int out_size, void* d_ws, size_t ws_size,
                              hipStream_t stream){
  const float* x    = (const float*)d_in[0];
  const float* temb = (const float*)d_in[1];
  const int*   neigh= (const int*)d_in[2];
  const float* gn1w = (const float*)d_in[3];
  const float* gn1b = (const float*)d_in[4];
  const float* w1   = (const float*)d_in[5];
  const float* b1   = (const float*)d_in[6];
  const float* wt   = (const float*)d_in[7];
  const float* bt   = (const float*)d_in[8];
  const float* gn2w = (const float*)d_in[9];
  const float* gn2b = (const float*)d_in[10];
  const float* w2   = (const float*)d_in[11];
  const float* b2   = (const float*)d_in[12];
  const float* wsm  = (const float*)d_in[13];
  const float* bs   = (const float*)d_in[14];
  float* out = (float*)d_out;

  char* wsp = (char*)d_ws;
  unsigned short* act1 = (unsigned short*)(wsp);                       // 32 MiB
  unsigned short* xb   = (unsigned short*)(wsp + 33554432);            // 32 MiB
  unsigned short* h1   = (unsigned short*)(wsp + 67108864);            // 64 MiB
  unsigned short* W1b  = (unsigned short*)(wsp + 134217728);           // 589824 B
  unsigned short* W2b  = (unsigned short*)(wsp + 134217728 + 589824);  // 1245184 B
  char* p = wsp + 134217728 + 589824 + 1245184;
  float* tc    = (float*)p;  p += 2048;
  float* part1 = (float*)p;  p += (size_t)Bb*32*NCH1*2*4;
  float* part2 = (float*)p;  p += (size_t)Bb*32*NCH2*2*4;
  float* sc1   = (float*)p;  p += 1024;
  float* bi1   = (float*)p;  p += 1024;
  float* sc2   = (float*)p;  p += 2048;
  float* bi2   = (float*)p;  p += 2048;

  k_gn1_partial<<<dim3(NCH1, Bb), 256, 0, stream>>>(x, part1);
  k_gn1_final  <<<1, 64, 0, stream>>>(part1, gn1w, gn1b, sc1, bi1);
  k_act1       <<<16384, 256, 0, stream>>>(x, sc1, bi1, act1, xb);
  k_prepW      <<<(W1N + W2N)/256, 256, 0, stream>>>(w1, w2, wsm, W1b, W2b);
  k_tcomb      <<<dim3(COUT/4, Bb), 256, 0, stream>>>(temb, wt, bt, b1, tc);
  k_conv<128, 18, 2, false><<<2048, 256, 0, stream>>>(act1, nullptr, W1b, neigh, tc, nullptr, nullptr, h1, nullptr);
  k_gn2_partial<<<dim3(NCH2, Bb), 256, 0, stream>>>(h1, part2);
  k_gn2_final  <<<1, 64, 0, stream>>>(part2, gn2w, gn2b, sc2, bi2);
  k_act2       <<<32768, 256, 0, stream>>>(h1, sc2, bi2);
  k_conv<256, 38, 4, true><<<2048, 256, 0, stream>>>(h1, xb, W2b, neigh, nullptr, b2, bs, nullptr, out);
}

// Round 4
// 601.226 us; speedup vs baseline: 1.4431x; 1.0398x over previous
//
#include <hip/hip_runtime.h>
#include <hip/hip_bf16.h>

#define DEV __device__ __forceinline__

typedef __attribute__((ext_vector_type(8))) short bf16x8;
typedef __attribute__((ext_vector_type(4))) float f32x4;

constexpr int Bb = 2, V = 65536, CIN = 128, COUT = 256, TDIM = 512;
constexpr float EPS = 1e-5f;
constexpr int K1 = 1152, K2 = 2304, K2e = 2432;
constexpr int NCH1 = 128;   // gn1 chunks (512 rows each)
constexpr int NCH2 = 256;   // gn2 chunks (256 rows each)
constexpr int W1N = (K1/8)*COUT*8;    // 294912
constexpr int W2N = (K2e/8)*COUT*8;   // 622592

DEV float silu_f(float x){ return x / (1.f + __expf(-x)); }
DEV unsigned short f2b(float x){
  union { float f; unsigned u; } v; v.f = x;
  unsigned r = v.u + 0x7fffu + ((v.u >> 16) & 1u);
  return (unsigned short)(r >> 16);
}
DEV float b2f(unsigned short h){ union { unsigned u; float f; } v; v.u = ((unsigned)h) << 16; return v.f; }

// ---------------- gn1 stats ----------------
__global__ void k_gn1_partial(const float* __restrict__ x, float* __restrict__ part){
  int b = blockIdx.y, ch = blockIdx.x;
  int t = threadIdx.x;            // 256
  int c = t & 127;
  int r0 = t >> 7;                // 0..1
  float s = 0.f, ss = 0.f;
  const float* xp = x + ((size_t)b*V + (size_t)ch*512)*CIN + c;
  for (int r = r0; r < 512; r += 2){
    float v = xp[(size_t)r*CIN];
    s += v; ss += v*v;
  }
  __shared__ float s_s[256], s_q[256];
  s_s[t] = s; s_q[t] = ss; __syncthreads();
  if (t < 128){ s_s[t] += s_s[t+128]; s_q[t] += s_q[t+128]; }
  __syncthreads();
  if (t < 32){
    float a = 0, q = 0;
    for (int i = 0; i < 4; ++i){ a += s_s[t*4+i]; q += s_q[t*4+i]; }
    int idx = ((b*32 + t)*NCH1 + ch)*2;
    part[idx] = a; part[idx+1] = q;
  }
}

__global__ void k_gn1_final(const float* __restrict__ part, const float* __restrict__ w,
                            const float* __restrict__ bias, float* __restrict__ sc,
                            float* __restrict__ bi){
  int t = threadIdx.x;  // 64 = b*32+g
  if (t >= Bb*32) return;
  float s = 0, q = 0;
  for (int ch = 0; ch < NCH1; ++ch){ s += part[(t*NCH1+ch)*2]; q += part[(t*NCH1+ch)*2+1]; }
  float n = (float)V * 4.f;
  float mean = s / n;
  float var = q / n - mean*mean;
  float inv = rsqrtf(var + EPS);
  int b = t >> 5, g = t & 31;
  for (int j = 0; j < 4; ++j){
    int c = g*4 + j;
    float scl = w[c] * inv;
    sc[b*CIN + c] = scl;
    bi[b*CIN + c] = bias[c] - mean*scl;
  }
}

// act1 = bf16(silu(gn1(x))), xb = bf16(x)
__global__ void k_act1(const float* __restrict__ x, const float* __restrict__ sc,
                       const float* __restrict__ bi, unsigned short* __restrict__ act1,
                       unsigned short* __restrict__ xb){
  size_t i = ((size_t)blockIdx.x*256 + threadIdx.x)*4;
  int c = (int)(i & (CIN-1));
  int b = (int)(i >> 23);
  float4 v = *(const float4*)(x + i);
  const float* scp = sc + b*CIN + c;
  const float* bip = bi + b*CIN + c;
  ushort4 a, xo;
  a.x = f2b(silu_f(v.x*scp[0] + bip[0]));
  a.y = f2b(silu_f(v.y*scp[1] + bip[1]));
  a.z = f2b(silu_f(v.z*scp[2] + bip[2]));
  a.w = f2b(silu_f(v.w*scp[3] + bip[3]));
  xo.x = f2b(v.x); xo.y = f2b(v.y); xo.z = f2b(v.z); xo.w = f2b(v.w);
  *(ushort4*)(act1 + i) = a;
  *(ushort4*)(xb + i)   = xo;
}

// W layouts: Wb[k8][o][j] = W[o][k8*8+j], bf16. W2b gets ws appended at k>=2304.
__global__ void k_prepW(const float* __restrict__ w1, const float* __restrict__ w2,
                        const float* __restrict__ wsm, unsigned short* __restrict__ W1b,
                        unsigned short* __restrict__ W2b){
  int i = blockIdx.x*256 + threadIdx.x;
  if (i < W1N){
    int j = i & 7, o = (i >> 3) & 255, k8 = i >> 11;
    W1b[i] = f2b(w1[o*K1 + k8*8 + j]);
  }
  int i2 = i - W1N;
  if (i2 >= 0 && i2 < W2N){
    int j = i2 & 7, o = (i2 >> 3) & 255, k8 = i2 >> 11;
    int k = k8*8 + j;
    float v = (k < K2) ? w2[o*K2 + k] : wsm[o*CIN + (k - K2)];
    W2b[i2] = f2b(v);
  }
}

// tcomb[b][o] = silu(t_emb[b]) @ wt[o] + bt[o] + b1[o]
// One wave per output: coalesced wt reads + shuffle reduce.
__global__ void k_tcomb(const float* __restrict__ temb, const float* __restrict__ wt,
                        const float* __restrict__ bt, const float* __restrict__ b1,
                        float* __restrict__ tc){
  int b = blockIdx.y;
  int o = blockIdx.x*4 + (threadIdx.x >> 6);
  int l = threadIdx.x & 63;
  const float* tb = temb + (size_t)b*TDIM;
  const float* wr = wt + (size_t)o*TDIM;
  float acc = 0.f;
  #pragma unroll
  for (int k = l; k < TDIM; k += 64)
    acc += silu_f(tb[k]) * wr[k];
  #pragma unroll
  for (int off = 32; off > 0; off >>= 1) acc += __shfl_down(acc, off, 64);
  if (l == 0) tc[b*COUT + o] = acc + bt[o] + b1[o];
}

// ------- gathered GEMM: A DMA->LDS double-buffered (counted vmcnt), B in regs -
// Tile: 128(M) x 128(N), 4 waves (each 64x64), BK=64, 16x16x32 bf16 MFMA.
// R3 established the hybrid (A via DMA/LDS single-buffer, B direct to regs):
// VGPR 64+64AGPR, LDS 21KB, Occ 37.5%, MfmaUtil 38.5% -- the remaining stall
// is the serial per-chunk gather drain (__syncthreads lowers to vmcnt(0)).
// This round: A-only LDS double-buffer (+16KB -> 36.6KB, still 4 blocks/CU)
// with counted vmcnt + RAW barriers (T3/T4 minimum 2-phase; counting machinery
// proven correct in R1 on this kernel):
//   per iter t: [8 B(t) loads] [4 DMA A(t+1)->buf^1] vmcnt(12) (retires A(t)'s
//   4 DMAs, leaves A(t+1) in flight) s_barrier COMPUTE(t) s_barrier.
// The compiler's own counted wait for bv (register dep) also leaves A(t+1)
// outstanding. No vmcnt(0) anywhere in the loop.
// A-LDS: 128 rows x 64 el, XOR segment swizzle: slot s of row r holds global
// segment s^(r&7); DMA dst = uniform base + lane*16B (m104/m108), the source
// address carries the swizzle.
// XCD pair swizzle: blocks (bx,n0=0)/(bx,n0=128) gather the SAME 128x9 rows;
// mapped 8 dispatches apart -> same XCD -> L2 gather reuse (FETCH 595->303MB).
template<int CINR, int NCHUNK, int CPN, bool CONV2>
__launch_bounds__(256, 4)
__global__ void k_conv(const unsigned short* __restrict__ act,
                       const unsigned short* __restrict__ xb,
                       const unsigned short* __restrict__ Wb,
                       const int* __restrict__ neigh,
                       const float* __restrict__ tc,
                       const float* __restrict__ b2,
                       const float* __restrict__ bs,
                       unsigned short* __restrict__ outb,
                       float* __restrict__ outf){
  __shared__ __align__(16) unsigned short A_lds[2][128*64];
  __shared__ int nb[128*9];
  const int tid = threadIdx.x;
  const int w = tid >> 6, lane = tid & 63;
  const int d = blockIdx.x;                    // 0..2047
  const int bx = ((d >> 4) << 3) + (d & 7);    // row-block 0..1023
  const int n0 = ((d >> 3) & 1) << 7;          // N-half; pair d,d+8 -> same XCD
  const int vflat = bx << 7;
  const int b = vflat >> 16;          // / V
  const int vb = vflat & (V-1);
  for (int i = tid; i < 128*9; i += 256) nb[i] = neigh[(size_t)vb*9 + i];

  f32x4 acc[4][4] = {};
  const int wm = w >> 1, wn = w & 1;
  const int quad = lane >> 4, l15 = lane & 15;
  const int sr = lane >> 3, ssg = lane & 7;

  const unsigned short* actb = act + (size_t)b*V*CINR;
  const unsigned short* xbb  = CONV2 ? (xb + (size_t)b*V*CIN) : (const unsigned short*)nullptr;
  // per-lane base into Wb for this wave's N-columns and k-slice quad
  const unsigned short* wq = Wb + (size_t)quad*COUT*8 + (size_t)(n0 + (wn<<6) + l15)*8;

  // stage chunk's gathered A rows into buf via DMA: 4 issues/wave
  auto STAGE_A = [&](int chunk, int buf){
    const bool scseg = CONV2 && (chunk >= NCHUNK-2);
    int nidx = 0, c0, rl;
    const unsigned short* src;
    if (scseg){ c0 = (chunk - (NCHUNK-2))*64; src = xbb; rl = CIN; }
    else      { nidx = chunk / CPN; c0 = (chunk % CPN)*64; src = actb; rl = CINR; }
    #pragma unroll
    for (int i = 0; i < 4; ++i){
      int row  = (w<<5) + (i<<3) + sr;
      int rowg = scseg ? (vb + row) : nb[row*9 + nidx];
      int g = ssg ^ (row & 7);
      const unsigned short* gp = src + (size_t)rowg*rl + c0 + g*8;   // per-lane src
      unsigned short* lp = &A_lds[buf][((w<<5) + (i<<3))<<6];        // uniform dst
      __builtin_amdgcn_global_load_lds(gp, lp, 16, 0, 0);
    }
  };

  auto LOADB = [&](int chunk, bf16x8 (&bv)[8]){
    const unsigned short* wp = wq + (size_t)chunk*8*COUT*8;
    #pragma unroll
    for (int nt = 0; nt < 4; ++nt){
      bv[nt*2+0] = *(const bf16x8*)(wp + (nt<<7));               // ks=0
      bv[nt*2+1] = *(const bf16x8*)(wp + 4*COUT*8 + (nt<<7));    // ks=1
    }
  };

  auto COMPUTE = [&](int cur, bf16x8 (&bv)[8]){
    __builtin_amdgcn_s_setprio(1);
    #pragma unroll
    for (int ks = 0; ks < 2; ++ks){
      bf16x8 av[4];
      #pragma unroll
      for (int mt = 0; mt < 4; ++mt){
        int m = (wm<<6) + (mt<<4) + l15;
        int seg = ((ks<<2) + quad) ^ (l15 & 7);    // undo swizzle (m&7 == l15&7)
        av[mt] = *(const bf16x8*)&A_lds[cur][(m<<6) + (seg<<3)];
      }
      #pragma unroll
      for (int mt = 0; mt < 4; ++mt)
        #pragma unroll
        for (int nt = 0; nt < 4; ++nt)
          acc[mt][nt] = __builtin_amdgcn_mfma_f32_16x16x32_bf16(av[mt], bv[nt*2+ks], acc[mt][nt], 0, 0, 0);
    }
    __builtin_amdgcn_s_setprio(0);
  };

  __syncthreads();          // nb visible (full drain, before any DMA: count clean)
  STAGE_A(0, 0);            // 4 DMA in flight

  #pragma unroll 1
  for (int t = 0; t < NCHUNK-1; ++t){
    const int cur = t & 1;
    bf16x8 bv[8];
    LOADB(t, bv);                                    // 8 loads (older than DMA below)
    STAGE_A(t+1, cur^1);                             // 4 DMA prefetch
    asm volatile("s_waitcnt vmcnt(12)" ::: "memory");// retire A(t)'s DMAs only
    __builtin_amdgcn_s_barrier();                    // raw: A(t) visible to all
    asm volatile("" ::: "memory");
    COMPUTE(cur, bv);                                // compiler waits bv (leaves A(t+1))
    asm volatile("" ::: "memory");
    __builtin_amdgcn_s_barrier();                    // buf[cur] reads done (WAR)
    asm volatile("" ::: "memory");
  }
  { // peeled last chunk: nothing left to prefetch
    bf16x8 bv[8];
    LOADB(NCHUNK-1, bv);
    asm volatile("s_waitcnt vmcnt(8)" ::: "memory"); // retire A(NCHUNK-1)'s DMAs
    __builtin_amdgcn_s_barrier();
    asm volatile("" ::: "memory");
    COMPUTE((NCHUNK-1) & 1, bv);
  }

  // ---- epilogue: C/D layout col=lane&15, row=quad*4+reg (m89-verified)
  #pragma unroll
  for (int mt = 0; mt < 4; ++mt){
    #pragma unroll
    for (int nt = 0; nt < 4; ++nt){
      int col = n0 + (wn<<6) + (nt<<4) + l15;
      float bval = CONV2 ? (b2[col] + bs[col]) : tc[b*COUT + col];
      #pragma unroll
      for (int rg = 0; rg < 4; ++rg){
        int row = (wm<<6) + (mt<<4) + (quad<<2) + rg;
        size_t off = ((size_t)(vflat + row))*COUT + col;
        float v = acc[mt][nt][rg] + bval;
        if (CONV2) outf[off] = v;
        else       outb[off] = f2b(v);
      }
    }
  }
}

// ---------------- gn2 stats on bf16 h1 ----------------
__global__ void k_gn2_partial(const unsigned short* __restrict__ h1, float* __restrict__ part){
  int b = blockIdx.y, ch = blockIdx.x;
  int t = threadIdx.x;  // 256 = channel
  float s = 0.f, ss = 0.f;
  const unsigned short* p = h1 + ((size_t)b*V + (size_t)ch*256)*COUT + t;
  for (int r = 0; r < 256; ++r){
    float v = b2f(p[(size_t)r*COUT]);
    s += v; ss += v*v;
  }
  __shared__ float s_s[256], s_q[256];
  s_s[t] = s; s_q[t] = ss; __syncthreads();
  if (t < 32){
    float a = 0, q = 0;
    for (int i = 0; i < 8; ++i){ a += s_s[t*8+i]; q += s_q[t*8+i]; }
    int idx = ((b*32 + t)*NCH2 + ch)*2;
    part[idx] = a; part[idx+1] = q;
  }
}

__global__ void k_gn2_final(const float* __restrict__ part, const float* __restrict__ w,
                            const float* __restrict__ bias, float* __restrict__ sc,
                            float* __restrict__ bi){
  int t = threadIdx.x;
  if (t >= Bb*32) return;
  float s = 0, q = 0;
  for (int ch = 0; ch < NCH2; ++ch){ s += part[(t*NCH2+ch)*2]; q += part[(t*NCH2+ch)*2+1]; }
  float n = (float)V * 8.f;
  float mean = s / n, var = q / n - mean*mean, inv = rsqrtf(var + EPS);
  int b = t >> 5, g = t & 31;
  for (int j = 0; j < 8; ++j){
    int c = g*8 + j;
    float scl = w[c] * inv;
    sc[b*COUT + c] = scl;
    bi[b*COUT + c] = bias[c] - mean*scl;
  }
}

// act2 = silu(gn2(h1)) in place (bf16)
__global__ void k_act2(unsigned short* __restrict__ h1, const float* __restrict__ sc,
                       const float* __restrict__ bi){
  size_t i = ((size_t)blockIdx.x*256 + threadIdx.x)*4;
  int c = (int)(i & (COUT-1));
  int b = (int)(i >> 24);
  ushort4 h = *(ushort4*)(h1 + i);
  const float* scp = sc + b*COUT + c;
  const float* bip = bi + b*COUT + c;
  ushort4 o;
  o.x = f2b(silu_f(b2f(h.x)*scp[0] + bip[0]));
  o.y = f2b(silu_f(b2f(h.y)*scp[1] + bip[1]));
  o.z = f2b(silu_f(b2f(h.z)*scp[2] + bip[2]));
  o.w = f2b(silu_f(b2f(h.w)*scp[3] + bip[3]));
  *(ushort4*)(h1 + i) = o;
}

extern "C" void kernel_launch(void* const* d_in, const int* in_sizes, int n_in,
                              void* d_out, int out_size, void* d_ws, size_t ws_size,
                              hipStream_t stream){
  const float* x    = (const float*)d_in[0];
  const float* temb = (const float*)d_in[1];
  const int*   neigh= (const int*)d_in[2];
  const float* gn1w = (const float*)d_in[3];
  const float* gn1b = (const float*)d_in[4];
  const float* w1   = (const float*)d_in[5];
  const float* b1   = (const float*)d_in[6];
  const float* wt   = (const float*)d_in[7];
  const float* bt   = (const float*)d_in[8];
  const float* gn2w = (const float*)d_in[9];
  const float* gn2b = (const float*)d_in[10];
  const float* w2   = (const float*)d_in[11];
  const float* b2   = (const float*)d_in[12];
  const float* wsm  = (const float*)d_in[13];
  const float* bs   = (const float*)d_in[14];
  float* out = (float*)d_out;

  char* wsp = (char*)d_ws;
  unsigned short* act1 = (unsigned short*)(wsp);                       // 32 MiB
  unsigned short* xb   = (unsigned short*)(wsp + 33554432);            // 32 MiB
  unsigned short* h1   = (unsigned short*)(wsp + 67108864);            // 64 MiB
  unsigned short* W1b  = (unsigned short*)(wsp + 134217728);           // 589824 B
  unsigned short* W2b  = (unsigned short*)(wsp + 134217728 + 589824);  // 1245184 B
  char* p = wsp + 134217728 + 589824 + 1245184;
  float* tc    = (float*)p;  p += 2048;
  float* part1 = (float*)p;  p += (size_t)Bb*32*NCH1*2*4;
  float* part2 = (float*)p;  p += (size_t)Bb*32*NCH2*2*4;
  float* sc1   = (float*)p;  p += 1024;
  float* bi1   = (float*)p;  p += 1024;
  float* sc2   = (float*)p;  p += 2048;
  float* bi2   = (float*)p;  p += 2048;

  k_gn1_partial<<<dim3(NCH1, Bb), 256, 0, stream>>>(x, part1);
  k_gn1_final  <<<1, 64, 0, stream>>>(part1, gn1w, gn1b, sc1, bi1);
  k_act1       <<<16384, 256, 0, stream>>>(x, sc1, bi1, act1, xb);
  k_prepW      <<<(W1N + W2N)/256, 256, 0, stream>>>(w1, w2, wsm, W1b, W2b);
  k_tcomb      <<<dim3(COUT/4, Bb), 256, 0, stream>>>(temb, wt, bt, b1, tc);
  k_conv<128, 18, 2, false><<<2048, 256, 0, stream>>>(act1, nullptr, W1b, neigh, tc, nullptr, nullptr, h1, nullptr);
  k_gn2_partial<<<dim3(NCH2, Bb), 256, 0, stream>>>(h1, part2);
  k_gn2_final  <<<1, 64, 0, stream>>>(part2, gn2w, gn2b, sc2, bi2);
  k_act2       <<<32768, 256, 0, stream>>>(h1, sc2, bi2);
  k_conv<256, 38, 4, true><<<2048, 256, 0, stream>>>(h1, xb, W2b, neigh, nullptr, b2, bs, nullptr, out);
}

// Round 5
// 542.385 us; speedup vs baseline: 1.5997x; 1.1085x over previous
//
#include <hip/hip_runtime.h>
#include <hip/hip_bf16.h>

#define DEV __device__ __forceinline__

typedef __attribute__((ext_vector_type(8))) short bf16x8;
typedef __attribute__((ext_vector_type(4))) float f32x4;

constexpr int Bb = 2, V = 65536, CIN = 128, COUT = 256, TDIM = 512;
constexpr float EPS = 1e-5f;
constexpr int K1 = 1152, K2 = 2304, K2e = 2432;
constexpr int NCH1 = 128;   // gn1 chunks (512 rows each)
constexpr int NCH2 = 256;   // gn2 chunks (256 rows each)
constexpr int W1N = (K1/8)*COUT*8;    // 294912
constexpr int W2N = (K2e/8)*COUT*8;   // 622592

DEV float silu_f(float x){ return x / (1.f + __expf(-x)); }
DEV unsigned short f2b(float x){
  union { float f; unsigned u; } v; v.f = x;
  unsigned r = v.u + 0x7fffu + ((v.u >> 16) & 1u);
  return (unsigned short)(r >> 16);
}
DEV float b2f(unsigned short h){ union { unsigned u; float f; } v; v.u = ((unsigned)h) << 16; return v.f; }

// ---------------- gn1 stats (float4: group = 4 consecutive ch = one float4) ---
__global__ void k_gn1_partial(const float* __restrict__ x, float* __restrict__ part){
  int b = blockIdx.y, ch = blockIdx.x;
  int t = threadIdx.x;            // 256
  int g  = t & 31;                // group index == float4 index (4 ch/group)
  int r0 = t >> 5;                // 0..7
  float s = 0.f, ss = 0.f;
  const float4* xp = (const float4*)(x + ((size_t)b*V + (size_t)ch*512)*CIN) + g;
  for (int r = r0; r < 512; r += 8){
    float4 v = xp[(size_t)r*32];
    s  += v.x + v.y + v.z + v.w;
    ss += v.x*v.x + v.y*v.y + v.z*v.z + v.w*v.w;
  }
  __shared__ float s_s[8][32], s_q[8][32];
  s_s[r0][g] = s; s_q[r0][g] = ss; __syncthreads();
  if (t < 32){
    float a = 0, q = 0;
    #pragma unroll
    for (int i = 0; i < 8; ++i){ a += s_s[i][t]; q += s_q[i][t]; }
    int idx = ((b*32 + t)*NCH1 + ch)*2;
    part[idx] = a; part[idx+1] = q;
  }
}

__global__ void k_gn1_final(const float* __restrict__ part, const float* __restrict__ w,
                            const float* __restrict__ bias, float* __restrict__ sc,
                            float* __restrict__ bi){
  int t = threadIdx.x;  // 64 = b*32+g
  if (t >= Bb*32) return;
  float s = 0, q = 0;
  for (int ch = 0; ch < NCH1; ++ch){ s += part[(t*NCH1+ch)*2]; q += part[(t*NCH1+ch)*2+1]; }
  float n = (float)V * 4.f;
  float mean = s / n;
  float var = q / n - mean*mean;
  float inv = rsqrtf(var + EPS);
  int b = t >> 5, g = t & 31;
  for (int j = 0; j < 4; ++j){
    int c = g*4 + j;
    float scl = w[c] * inv;
    sc[b*CIN + c] = scl;
    bi[b*CIN + c] = bias[c] - mean*scl;
  }
}

// act1 = bf16(silu(gn1(x))), xb = bf16(x)
__global__ void k_act1(const float* __restrict__ x, const float* __restrict__ sc,
                       const float* __restrict__ bi, unsigned short* __restrict__ act1,
                       unsigned short* __restrict__ xb){
  size_t i = ((size_t)blockIdx.x*256 + threadIdx.x)*4;
  int c = (int)(i & (CIN-1));
  int b = (int)(i >> 23);
  float4 v = *(const float4*)(x + i);
  const float* scp = sc + b*CIN + c;
  const float* bip = bi + b*CIN + c;
  ushort4 a, xo;
  a.x = f2b(silu_f(v.x*scp[0] + bip[0]));
  a.y = f2b(silu_f(v.y*scp[1] + bip[1]));
  a.z = f2b(silu_f(v.z*scp[2] + bip[2]));
  a.w = f2b(silu_f(v.w*scp[3] + bip[3]));
  xo.x = f2b(v.x); xo.y = f2b(v.y); xo.z = f2b(v.z); xo.w = f2b(v.w);
  *(ushort4*)(act1 + i) = a;
  *(ushort4*)(xb + i)   = xo;
}

// W layouts: Wb[k8][o][j] = W[o][k8*8+j], bf16. W2b gets ws appended at k>=2304.
__global__ void k_prepW(const float* __restrict__ w1, const float* __restrict__ w2,
                        const float* __restrict__ wsm, unsigned short* __restrict__ W1b,
                        unsigned short* __restrict__ W2b){
  int i = blockIdx.x*256 + threadIdx.x;
  if (i < W1N){
    int j = i & 7, o = (i >> 3) & 255, k8 = i >> 11;
    W1b[i] = f2b(w1[o*K1 + k8*8 + j]);
  }
  int i2 = i - W1N;
  if (i2 >= 0 && i2 < W2N){
    int j = i2 & 7, o = (i2 >> 3) & 255, k8 = i2 >> 11;
    int k = k8*8 + j;
    float v = (k < K2) ? w2[o*K2 + k] : wsm[o*CIN + (k - K2)];
    W2b[i2] = f2b(v);
  }
}

// tcomb[b][o] = silu(t_emb[b]) @ wt[o] + bt[o] + b1[o]
// One wave per output: coalesced wt reads + shuffle reduce.
__global__ void k_tcomb(const float* __restrict__ temb, const float* __restrict__ wt,
                        const float* __restrict__ bt, const float* __restrict__ b1,
                        float* __restrict__ tc){
  int b = blockIdx.y;
  int o = blockIdx.x*4 + (threadIdx.x >> 6);
  int l = threadIdx.x & 63;
  const float* tb = temb + (size_t)b*TDIM;
  const float* wr = wt + (size_t)o*TDIM;
  float acc = 0.f;
  #pragma unroll
  for (int k = l; k < TDIM; k += 64)
    acc += silu_f(tb[k]) * wr[k];
  #pragma unroll
  for (int off = 32; off > 0; off >>= 1) acc += __shfl_down(acc, off, 64);
  if (l == 0) tc[b*COUT + o] = acc + bt[o] + b1[o];
}

// ------- gathered GEMM: merged-N block (M=128 x N=256), 8 waves, A dbuf -------
// R4 post-mortem: with 16 waves/CU + counted vmcnt, latency is mostly covered;
// the cost is gather REQUEST volume -- and the XCD-paired block duplicated
// every A-gather (served by L2, but 2x the queue traffic + DMA issues).
// This round: one 512-thread block covers the full N=256, staging A ONCE per
// chunk for all 256 columns -> chip-wide A-gather requests, nb loads, and DMA
// issues all halve. Per-wave work is IDENTICAL to R4 (64x64 subtile, 32 MFMA
// per chunk, bv[8], acc 64 AGPR): wave (wm=w>>2, wn=w&3).
// Residency unchanged: VGPR ~128-unified -> 4 waves/SIMD; LDS 36.6KB ->
// 2 blocks/CU x 8 waves = 16 waves/CU.
// Pipeline (proven R1/R4): per iter t: [8 B(t) loads][2 DMA A(t+1)->buf^1]
// vmcnt(10) (retires A(t)'s 2 DMAs, leaves B(t)+A(t+1)) s_barrier COMPUTE
// s_barrier. No vmcnt(0) in the loop.
// A-LDS: 128 rows x 64 el, XOR segment swizzle (slot s of row r holds global
// segment s^(r&7)); DMA dst = uniform base + lane*16B, src carries swizzle.
template<int CINR, int NCHUNK, int CPN, bool CONV2>
__launch_bounds__(512, 4)
__global__ void k_conv(const unsigned short* __restrict__ act,
                       const unsigned short* __restrict__ xb,
                       const unsigned short* __restrict__ Wb,
                       const int* __restrict__ neigh,
                       const float* __restrict__ tc,
                       const float* __restrict__ b2,
                       const float* __restrict__ bs,
                       unsigned short* __restrict__ outb,
                       float* __restrict__ outf){
  __shared__ __align__(16) unsigned short A_lds[2][128*64];
  __shared__ int nb[128*9];
  const int tid = threadIdx.x;
  const int w = tid >> 6, lane = tid & 63;   // w: 0..7
  const int bx = blockIdx.x;                 // 0..1023
  const int vflat = bx << 7;
  const int b = vflat >> 16;          // / V
  const int vb = vflat & (V-1);
  for (int i = tid; i < 128*9; i += 512) nb[i] = neigh[(size_t)vb*9 + i];

  f32x4 acc[4][4] = {};
  const int wm = w >> 2, wn = w & 3;         // 2M x 4N wave grid
  const int quad = lane >> 4, l15 = lane & 15;
  const int sr = lane >> 3, ssg = lane & 7;

  const unsigned short* actb = act + (size_t)b*V*CINR;
  const unsigned short* xbb  = CONV2 ? (xb + (size_t)b*V*CIN) : (const unsigned short*)nullptr;
  // per-lane base into Wb for this wave's N-columns and k-slice quad
  const unsigned short* wq = Wb + (size_t)quad*COUT*8 + (size_t)((wn<<6) + l15)*8;

  // stage chunk's gathered A rows into buf via DMA: 2 issues/wave (16 rows/wave)
  auto STAGE_A = [&](int chunk, int buf){
    const bool scseg = CONV2 && (chunk >= NCHUNK-2);
    int nidx = 0, c0, rl;
    const unsigned short* src;
    if (scseg){ c0 = (chunk - (NCHUNK-2))*64; src = xbb; rl = CIN; }
    else      { nidx = chunk / CPN; c0 = (chunk % CPN)*64; src = actb; rl = CINR; }
    #pragma unroll
    for (int i = 0; i < 2; ++i){
      int row  = (w<<4) + (i<<3) + sr;
      int rowg = scseg ? (vb + row) : nb[row*9 + nidx];
      int g = ssg ^ (row & 7);
      const unsigned short* gp = src + (size_t)rowg*rl + c0 + g*8;   // per-lane src
      unsigned short* lp = &A_lds[buf][((w<<4) + (i<<3))<<6];        // uniform dst
      __builtin_amdgcn_global_load_lds(gp, lp, 16, 0, 0);
    }
  };

  auto LOADB = [&](int chunk, bf16x8 (&bv)[8]){
    const unsigned short* wp = wq + (size_t)chunk*8*COUT*8;
    #pragma unroll
    for (int nt = 0; nt < 4; ++nt){
      bv[nt*2+0] = *(const bf16x8*)(wp + (nt<<7));               // ks=0
      bv[nt*2+1] = *(const bf16x8*)(wp + 4*COUT*8 + (nt<<7));    // ks=1
    }
  };

  auto COMPUTE = [&](int cur, bf16x8 (&bv)[8]){
    __builtin_amdgcn_s_setprio(1);
    #pragma unroll
    for (int ks = 0; ks < 2; ++ks){
      bf16x8 av[4];
      #pragma unroll
      for (int mt = 0; mt < 4; ++mt){
        int m = (wm<<6) + (mt<<4) + l15;
        int seg = ((ks<<2) + quad) ^ (l15 & 7);    // undo swizzle (m&7 == l15&7)
        av[mt] = *(const bf16x8*)&A_lds[cur][(m<<6) + (seg<<3)];
      }
      #pragma unroll
      for (int mt = 0; mt < 4; ++mt)
        #pragma unroll
        for (int nt = 0; nt < 4; ++nt)
          acc[mt][nt] = __builtin_amdgcn_mfma_f32_16x16x32_bf16(av[mt], bv[nt*2+ks], acc[mt][nt], 0, 0, 0);
    }
    __builtin_amdgcn_s_setprio(0);
  };

  __syncthreads();          // nb visible (full drain, before any DMA: count clean)
  STAGE_A(0, 0);            // 2 DMA in flight

  #pragma unroll 1
  for (int t = 0; t < NCHUNK-1; ++t){
    const int cur = t & 1;
    bf16x8 bv[8];
    LOADB(t, bv);                                    // 8 loads (after A(t)'s 2 DMA)
    STAGE_A(t+1, cur^1);                             // 2 DMA prefetch
    asm volatile("s_waitcnt vmcnt(10)" ::: "memory");// retire A(t)'s DMAs only
    __builtin_amdgcn_s_barrier();                    // raw: A(t) visible to all
    asm volatile("" ::: "memory");
    COMPUTE(cur, bv);                                // compiler waits bv (leaves A(t+1))
    asm volatile("" ::: "memory");
    __builtin_amdgcn_s_barrier();                    // buf[cur] reads done (WAR)
    asm volatile("" ::: "memory");
  }
  { // peeled last chunk: nothing left to prefetch
    bf16x8 bv[8];
    LOADB(NCHUNK-1, bv);
    asm volatile("s_waitcnt vmcnt(8)" ::: "memory"); // retire A(NCHUNK-1)'s DMAs
    __builtin_amdgcn_s_barrier();
    asm volatile("" ::: "memory");
    COMPUTE((NCHUNK-1) & 1, bv);
  }

  // ---- epilogue: C/D layout col=lane&15, row=quad*4+reg (m89-verified)
  #pragma unroll
  for (int mt = 0; mt < 4; ++mt){
    #pragma unroll
    for (int nt = 0; nt < 4; ++nt){
      int col = (wn<<6) + (nt<<4) + l15;
      float bval = CONV2 ? (b2[col] + bs[col]) : tc[b*COUT + col];
      #pragma unroll
      for (int rg = 0; rg < 4; ++rg){
        int row = (wm<<6) + (mt<<4) + (quad<<2) + rg;
        size_t off = ((size_t)(vflat + row))*COUT + col;
        float v = acc[mt][nt][rg] + bval;
        if (CONV2) outf[off] = v;
        else       outb[off] = f2b(v);
      }
    }
  }
}

// -------- gn2 stats on bf16 h1 (bf16x8: group = 8 consecutive ch = one bf16x8) -
__global__ void k_gn2_partial(const unsigned short* __restrict__ h1, float* __restrict__ part){
  int b = blockIdx.y, ch = blockIdx.x;
  int t = threadIdx.x;            // 256
  int g  = t & 31;                // group index == bf16x8 index (8 ch/group)
  int r0 = t >> 5;                // 0..7
  float s = 0.f, ss = 0.f;
  const unsigned short* p = h1 + ((size_t)b*V + (size_t)ch*256)*COUT + g*8;
  for (int r = r0; r < 256; r += 8){
    bf16x8 hv = *(const bf16x8*)(p + (size_t)r*COUT);
    #pragma unroll
    for (int j = 0; j < 8; ++j){
      float v = b2f((unsigned short)hv[j]);
      s += v; ss += v*v;
    }
  }
  __shared__ float s_s[8][32], s_q[8][32];
  s_s[r0][g] = s; s_q[r0][g] = ss; __syncthreads();
  if (t < 32){
    float a = 0, q = 0;
    #pragma unroll
    for (int i = 0; i < 8; ++i){ a += s_s[i][t]; q += s_q[i][t]; }
    int idx = ((b*32 + t)*NCH2 + ch)*2;
    part[idx] = a; part[idx+1] = q;
  }
}

__global__ void k_gn2_final(const float* __restrict__ part, const float* __restrict__ w,
                            const float* __restrict__ bias, float* __restrict__ sc,
                            float* __restrict__ bi){
  int t = threadIdx.x;
  if (t >= Bb*32) return;
  float s = 0, q = 0;
  for (int ch = 0; ch < NCH2; ++ch){ s += part[(t*NCH2+ch)*2]; q += part[(t*NCH2+ch)*2+1]; }
  float n = (float)V * 8.f;
  float mean = s / n, var = q / n - mean*mean, inv = rsqrtf(var + EPS);
  int b = t >> 5, g = t & 31;
  for (int j = 0; j < 8; ++j){
    int c = g*8 + j;
    float scl = w[c] * inv;
    sc[b*COUT + c] = scl;
    bi[b*COUT + c] = bias[c] - mean*scl;
  }
}

// act2 = silu(gn2(h1)) in place (bf16), 16B/lane
__global__ void k_act2(unsigned short* __restrict__ h1, const float* __restrict__ sc,
                       const float* __restrict__ bi){
  size_t i = ((size_t)blockIdx.x*256 + threadIdx.x)*8;
  int c = (int)(i & (COUT-1));
  int b = (int)(i >> 24);
  bf16x8 h = *(const bf16x8*)(h1 + i);
  const float* scp = sc + b*COUT + c;
  const float* bip = bi + b*COUT + c;
  bf16x8 o;
  #pragma unroll
  for (int j = 0; j < 8; ++j)
    o[j] = (short)f2b(silu_f(b2f((unsigned short)h[j])*scp[j] + bip[j]));
  *(bf16x8*)(h1 + i) = o;
}

extern "C" void kernel_launch(void* const* d_in, const int* in_sizes, int n_in,
                              void* d_out, int out_size, void* d_ws, size_t ws_size,
                              hipStream_t stream){
  const float* x    = (const float*)d_in[0];
  const float* temb = (const float*)d_in[1];
  const int*   neigh= (const int*)d_in[2];
  const float* gn1w = (const float*)d_in[3];
  const float* gn1b = (const float*)d_in[4];
  const float* w1   = (const float*)d_in[5];
  const float* b1   = (const float*)d_in[6];
  const float* wt   = (const float*)d_in[7];
  const float* bt   = (const float*)d_in[8];
  const float* gn2w = (const float*)d_in[9];
  const float* gn2b = (const float*)d_in[10];
  const float* w2   = (const float*)d_in[11];
  const float* b2   = (const float*)d_in[12];
  const float* wsm  = (const float*)d_in[13];
  const float* bs   = (const float*)d_in[14];
  float* out = (float*)d_out;

  char* wsp = (char*)d_ws;
  unsigned short* act1 = (unsigned short*)(wsp);                       // 32 MiB
  unsigned short* xb   = (unsigned short*)(wsp + 33554432);            // 32 MiB
  unsigned short* h1   = (unsigned short*)(wsp + 67108864);            // 64 MiB
  unsigned short* W1b  = (unsigned short*)(wsp + 134217728);           // 589824 B
  unsigned short* W2b  = (unsigned short*)(wsp + 134217728 + 589824);  // 1245184 B
  char* p = wsp + 134217728 + 589824 + 1245184;
  float* tc    = (float*)p;  p += 2048;
  float* part1 = (float*)p;  p += (size_t)Bb*32*NCH1*2*4;
  float* part2 = (float*)p;  p += (size_t)Bb*32*NCH2*2*4;
  float* sc1   = (float*)p;  p += 1024;
  float* bi1   = (float*)p;  p += 1024;
  float* sc2   = (float*)p;  p += 2048;
  float* bi2   = (float*)p;  p += 2048;

  k_gn1_partial<<<dim3(NCH1, Bb), 256, 0, stream>>>(x, part1);
  k_gn1_final  <<<1, 64, 0, stream>>>(part1, gn1w, gn1b, sc1, bi1);
  k_act1       <<<16384, 256, 0, stream>>>(x, sc1, bi1, act1, xb);
  k_prepW      <<<(W1N + W2N)/256, 256, 0, stream>>>(w1, w2, wsm, W1b, W2b);
  k_tcomb      <<<dim3(COUT/4, Bb), 256, 0, stream>>>(temb, wt, bt, b1, tc);
  k_conv<128, 18, 2, false><<<1024, 512, 0, stream>>>(act1, nullptr, W1b, neigh, tc, nullptr, nullptr, h1, nullptr);
  k_gn2_partial<<<dim3(NCH2, Bb), 256, 0, stream>>>(h1, part2);
  k_gn2_final  <<<1, 64, 0, stream>>>(part2, gn2w, gn2b, sc2, bi2);
  k_act2       <<<16384, 256, 0, stream>>>(h1, sc2, bi2);
  k_conv<256, 38, 4, true><<<1024, 512, 0, stream>>>(h1, xb, W2b, neigh, nullptr, b2, bs, nullptr, out);
}